// Round 1
// baseline (241.248 us; speedup 1.0000x reference)
//
#include <hip/hip_runtime.h>

// SoftGlidingBoxes: for each (b, c, l) 256x256 image and scale s=1..8,
// sum of s-x-s sliding-window max (VALID), then relu(.)+1.
// x: [B=16, H=256, W=256, C=3, L=8] fp32 -> out: [16, 3, 8, 8] fp32.

namespace {
constexpr int Bn = 16, Hn = 256, Wn = 256, CHn = 24, Sn = 8;
constexpr int JT = 64;                   // output cols per block
constexpr int IT = 32;                   // output rows per block
constexpr int RCOLS = JT + Sn - 1;       // 71 cols staged (incl. halo)
constexpr int RW = 76;                   // padded ring row width (16B-aligned, bank-friendly)
constexpr int BDIM = 192;                // 24 ch x 8 strips
constexpr int ROW_ELEMS = RCOLS * CHn;   // 1704
constexpr int ROW_VEC4 = ROW_ELEMS / 4;  // 426
constexpr int OUT_N = Bn * CHn * Sn;     // 3072
}

__global__ __launch_bounds__(BDIM) void sgb_main(const float* __restrict__ x,
                                                 float* __restrict__ accum) {
  // 8-row ring, ch-major so compute-phase float4 reads are stride-1 per lane.
  __shared__ __align__(16) float ring[8][CHn][RW];

  const int jt   = blockIdx.x;   // 0..3
  const int band = blockIdx.y;   // 0..7
  const int b    = blockIdx.z;   // 0..15
  const int j0 = jt * JT;
  const int i0 = band * IT;
  const int tid = threadIdx.x;
  const int ch = tid >> 3;       // 0..23 (c*8 + l)
  const int strip = tid & 7;     // 0..7
  const int jb = strip << 3;     // local col base of this thread's 8-wide strip
  const int gjb = j0 + jb;       // global col base

  const bool jedge = (j0 + RCOLS > Wn);              // only last j-tile
  const int limit = jedge ? (Wn - j0) * CHn : ROW_ELEMS;  // valid elems per staged row

  float acc[Sn];
#pragma unroll
  for (int s = 0; s < Sn; ++s) acc[s] = 0.f;

  // Stage one global row segment (71 cols x 24 ch, contiguous 1704 floats)
  // into ring slot (r - i0) & 7, transposed to [ch][col]. Rows/cols past the
  // edge are written as 0 (only ever read inside masked-off windows).
  auto load_row = [&](int r) {
    const int slot = (r - i0) & 7;
    float* dst = &ring[slot][0][0];
    const bool rok = (r < Hn);
    const float* src = x + ((long)(b * Hn + r) * Wn + j0) * CHn;
    for (int t4 = tid; t4 < ROW_VEC4; t4 += BDIM) {
      const int e = t4 * 4;
      float4 v = make_float4(0.f, 0.f, 0.f, 0.f);
      if (rok && e < limit) v = *reinterpret_cast<const float4*>(src + e);
      dst[((e + 0) % CHn) * RW + (e + 0) / CHn] = v.x;
      dst[((e + 1) % CHn) * RW + (e + 1) / CHn] = v.y;
      dst[((e + 2) % CHn) * RW + (e + 2) / CHn] = v.z;
      dst[((e + 3) % CHn) * RW + (e + 3) / CHn] = v.w;
    }
  };

  // Prefill rows i0 .. i0+6 (slots 0..6). Disjoint writes; sync below covers them.
  for (int d = 0; d < 7; ++d) load_row(i0 + d);

  for (int ii = 0; ii < IT; ++ii) {
    load_row(i0 + ii + 7);   // slot (ii+7)&7 (dead row i0+ii-1 was last read pre-sync)
    __syncthreads();
    const int i = i0 + ii;

    // vm[j] = vertical running max over rows i..i+s-1 at local col jb+j.
    float vm[16];
    {
      const float4* rp = reinterpret_cast<const float4*>(&ring[ii & 7][ch][jb]);
      float4 a = rp[0], b4 = rp[1], c4 = rp[2], d4 = rp[3];
      vm[0] = a.x;  vm[1] = a.y;  vm[2] = a.z;  vm[3] = a.w;
      vm[4] = b4.x; vm[5] = b4.y; vm[6] = b4.z; vm[7] = b4.w;
      vm[8] = c4.x; vm[9] = c4.y; vm[10] = c4.z; vm[11] = c4.w;
      vm[12] = d4.x; vm[13] = d4.y; vm[14] = d4.z; vm[15] = d4.w;
    }

    // s = 1: pooled == x; every (i, gj) with gj <= 255 is valid.
    acc[0] += ((vm[0] + vm[1]) + (vm[2] + vm[3])) + ((vm[4] + vm[5]) + (vm[6] + vm[7]));

#pragma unroll
    for (int s = 2; s <= Sn; ++s) {
      const float4* rp =
          reinterpret_cast<const float4*>(&ring[(ii + s - 1) & 7][ch][jb]);
      float4 a = rp[0], b4 = rp[1], c4 = rp[2], d4 = rp[3];
      float t[16];
      t[0] = a.x;  t[1] = a.y;  t[2] = a.z;  t[3] = a.w;
      t[4] = b4.x; t[5] = b4.y; t[6] = b4.z; t[7] = b4.w;
      t[8] = c4.x; t[9] = c4.y; t[10] = c4.z; t[11] = c4.w;
      t[12] = d4.x; t[13] = d4.y; t[14] = d4.z; t[15] = d4.w;
#pragma unroll
      for (int j = 0; j < 16; ++j) vm[j] = fmaxf(vm[j], t[j]);

      if (i + s <= Hn) {           // wave-uniform row-validity guard
        float sum = 0.f;
        if (jedge) {               // block-uniform; only last j-tile masks cols
#pragma unroll
          for (int j = 0; j < 8; ++j) {
            float p = vm[j];
#pragma unroll
            for (int d = 1; d < s; ++d) p = fmaxf(p, vm[j + d]);
            sum += (gjb + j + s <= Wn) ? p : 0.f;
          }
        } else {
#pragma unroll
          for (int j = 0; j < 8; ++j) {
            float p = vm[j];
#pragma unroll
            for (int d = 1; d < s; ++d) p = fmaxf(p, vm[j + d]);
            sum += p;
          }
        }
        acc[s - 1] += sum;
      }
    }
    __syncthreads();   // protect slot (ii)&7 before next iteration's load overwrites slot (ii+8)&7
  }

  // Reduce the 8 strips of each (ch, s) — lanes [8k, 8k+7] within a wave share ch.
#pragma unroll
  for (int s = 0; s < Sn; ++s) {
    float v = acc[s];
    v += __shfl_down(v, 4);
    v += __shfl_down(v, 2);
    v += __shfl_down(v, 1);
    if (strip == 0) atomicAdd(&accum[(b * CHn + ch) * Sn + s], v);
  }
}

__global__ void sgb_finalize(float* __restrict__ out) {
  const int i = blockIdx.x * blockDim.x + threadIdx.x;
  if (i < OUT_N) out[i] = fmaxf(out[i], 0.f) + 1.f;
}

extern "C" void kernel_launch(void* const* d_in, const int* in_sizes, int n_in,
                              void* d_out, int out_size, void* d_ws, size_t ws_size,
                              hipStream_t stream) {
  (void)in_sizes; (void)n_in; (void)d_ws; (void)ws_size; (void)out_size;
  const float* x = (const float*)d_in[0];
  float* out = (float*)d_out;

  // Accumulate directly into d_out (it's re-poisoned each call; zero it first).
  hipMemsetAsync(out, 0, OUT_N * sizeof(float), stream);
  dim3 grid(Wn / JT, Hn / IT, Bn);   // (4, 8, 16) = 512 blocks
  sgb_main<<<grid, BDIM, 0, stream>>>(x, out);
  sgb_finalize<<<(OUT_N + 255) / 256, 256, 0, stream>>>(out);
}

// Round 2
// 163.696 us; speedup vs baseline: 1.4738x; 1.4738x over previous
//
#include <hip/hip_runtime.h>
#include <math.h>

// SoftGlidingBoxes: for each (b, ch=c*8+l) 256x256 image and scale s=1..8,
// sum over valid positions of the s x s sliding-window max, then relu(.)+1.
// x: [16, 256, 256, 3, 8] fp32 -> out: [16, 3, 8, 8] fp32.
//
// Round-2 design: bottom-to-top register DP using
//   M_s[i][j] = max of four (s-1)-windows at (i,j),(i,j+1),(i+1,j),(i+1,j+1)
// Each thread owns (ch, 8-col strip); prev-row M_1..M_7 live in 56 VGPRs.
// Each input row is read from LDS exactly once (8 x b32, conflict-free via
// swizzled padding). One barrier per row (double-buffered row staging with
// perfectly coalesced float4 global loads).

namespace {
constexpr int Bn = 16, Hn = 256, Wn = 256, CHn = 24, Sn = 8;
constexpr int IT = 16;               // output rows per band
constexpr int NBANDS = Hn / IT;      // 16
constexpr int NSTRIP = 32;           // strips of 8 cols -> full 256-col width
constexpr int BDIM = CHn * NSTRIP;   // 768 threads = 12 waves
constexpr int ROWF = Wn * CHn;       // 6144 floats per image row
// LDS row layout: addr(c,ch) = c*25 + ch + (c>>3)*5  (max 6553)
// -> compute-read banks = (13*strip + ch) % 32 : full permutation, conflict-free
constexpr int LROW = 6560;
constexpr int OUT_N = Bn * CHn * Sn; // 3072
}

__device__ __forceinline__ int lds_addr(int c, int ch) {
  return c * 25 + ch + (c >> 3) * 5;
}

__global__ __launch_bounds__(BDIM, 3) void sgb_main(const float* __restrict__ x,
                                                    float* __restrict__ accum) {
  __shared__ float buf[2][LROW];

  const int band = blockIdx.x;
  const int b    = blockIdx.y;
  const int i0   = band * IT;
  const int tid  = threadIdx.x;
  const int ch    = tid >> 5;      // 0..23   (tid = ch*32 + strip)
  const int strip = tid & 31;      // 0..31, cols [strip*8, strip*8+8)
  const int rbase = strip * 205 + ch;          // lds_addr(strip*8, ch)
  // writer role: this thread stages row elements e = 8*tid .. 8*tid+7,
  // which are 8 consecutive ch of column cw = tid/3 -> contiguous in LDS.
  const int wbase = lds_addr(tid / 3, (tid % 3) * 8);

  float P[7][8];                   // prev-row M_1..M_7 for own 8 cols
#pragma unroll
  for (int s = 0; s < 7; ++s)
#pragma unroll
    for (int j = 0; j < 8; ++j) P[s][j] = -INFINITY;

  float acc[Sn];
#pragma unroll
  for (int s = 0; s < Sn; ++s) acc[s] = 0.f;

  const float* img = x + (long)(b * Hn) * ROWF;
  const int rhi = i0 + IT + 6;     // topmost staged row (may exceed H-1)

  // Prologue: stage row rhi into buf[0].
  if (rhi < Hn) {
    const float* src = img + rhi * ROWF + tid * 8;
    float4 v0 = reinterpret_cast<const float4*>(src)[0];
    float4 v1 = reinterpret_cast<const float4*>(src)[1];
    float* d = &buf[0][wbase];
    d[0] = v0.x; d[1] = v0.y; d[2] = v0.z; d[3] = v0.w;
    d[4] = v1.x; d[5] = v1.y; d[6] = v1.z; d[7] = v1.w;
  }

  for (int idx = 0; idx < IT + 7; ++idx) {
    const int r  = rhi - idx;      // current row (descending)
    const int pb = idx & 1;
    __syncthreads();               // staged writes of row r now visible

    // Issue next row's global loads early; LDS-write them after compute.
    const bool do_stage = (idx < IT + 6) && (r - 1 < Hn);
    float4 v0, v1;
    if (do_stage) {
      const float* src = img + (r - 1) * ROWF + tid * 8;
      v0 = reinterpret_cast<const float4*>(src)[0];
      v1 = reinterpret_cast<const float4*>(src)[1];
    }

    // cp = M_1[r] = x[r] at own 8 cols (LDS read, conflict-free).
    float cp[8];
    if (r < Hn) {
      const float* rb = &buf[pb][rbase];
#pragma unroll
      for (int k = 0; k < 8; ++k) cp[k] = rb[25 * k];
    } else {
#pragma unroll
      for (int k = 0; k < 8; ++k) cp[k] = -INFINITY;
    }

    const bool outrow = (r < i0 + IT);   // r >= i0 always holds
    if (outrow) {  // s=1: every col 0..255 is a valid window start
      acc[0] += ((cp[0] + cp[1]) + (cp[2] + cp[3])) +
                ((cp[4] + cp[5]) + (cp[6] + cp[7]));
    }

#pragma unroll
    for (int s = 2; s <= Sn; ++s) {
      // col-8 halo = right neighbor's col 0 (strip+1 == lane+1).
      // strip 31's pulls are garbage but land only in windows with
      // j+s>8, i.e. exactly the invalid (c+s>256) ones -> masked below.
      float nbNew = __shfl_down(cp[0], 1);        // new M_{s-1}[col 8]
      float nbOld = __shfl_down(P[s - 2][0], 1);  // prev-row M_{s-1}[col 8]
      float cc[8];
#pragma unroll
      for (int j = 0; j < 7; ++j)
        cc[j] = fmaxf(fmaxf(cp[j], cp[j + 1]),
                      fmaxf(P[s - 2][j], P[s - 2][j + 1]));
      cc[7] = fmaxf(fmaxf(cp[7], nbNew), fmaxf(P[s - 2][7], nbOld));

      if (outrow && (r + s <= Hn)) {
        float lo = 0.f, hi = 0.f;   // hi = windows needing cols past strip end
#pragma unroll
        for (int j = 0; j < 8; ++j) {
          if (j <= 8 - s) lo += cc[j]; else hi += cc[j];
        }
        acc[s - 1] += lo + (strip == NSTRIP - 1 ? 0.f : hi);
      }
#pragma unroll
      for (int j = 0; j < 8; ++j) { P[s - 2][j] = cp[j]; cp[j] = cc[j]; }
    }

    if (do_stage) {
      float* d = &buf[pb ^ 1][wbase];
      d[0] = v0.x; d[1] = v0.y; d[2] = v0.z; d[3] = v0.w;
      d[4] = v1.x; d[5] = v1.y; d[6] = v1.z; d[7] = v1.w;
    }
  }

  // Reduce 32 strips per ch (lanes [0,31] / [32,63] share ch) and accumulate.
#pragma unroll
  for (int s = 0; s < Sn; ++s) {
    float v = acc[s];
    v += __shfl_xor(v, 16);
    v += __shfl_xor(v, 8);
    v += __shfl_xor(v, 4);
    v += __shfl_xor(v, 2);
    v += __shfl_xor(v, 1);
    if (strip == 0) atomicAdd(&accum[(b * CHn + ch) * Sn + s], v);
  }
}

__global__ void sgb_finalize(float* __restrict__ out) {
  const int i = blockIdx.x * blockDim.x + threadIdx.x;
  if (i < OUT_N) out[i] = fmaxf(out[i], 0.f) + 1.f;
}

extern "C" void kernel_launch(void* const* d_in, const int* in_sizes, int n_in,
                              void* d_out, int out_size, void* d_ws, size_t ws_size,
                              hipStream_t stream) {
  (void)in_sizes; (void)n_in; (void)d_ws; (void)ws_size; (void)out_size;
  const float* x = (const float*)d_in[0];
  float* out = (float*)d_out;

  hipMemsetAsync(out, 0, OUT_N * sizeof(float), stream);
  dim3 grid(NBANDS, Bn);               // 16 x 16 = 256 blocks of 768 threads
  sgb_main<<<grid, BDIM, 0, stream>>>(x, out);
  sgb_finalize<<<(OUT_N + 255) / 256, 256, 0, stream>>>(out);
}